// Round 5
// baseline (641.971 us; speedup 1.0000x reference)
//
#include <hip/hip_runtime.h>

// HardBinaryVote: votes (63, N) int32 in {0,1}; weights (63,) fp32.
// out[j] = (sum_{v[i][j]==1} w[i]) > (sum_{v[i][j]==0} w[i]) ? 1 : 0  (int32)
//
// MEASUREMENT LEDGER (differential rounds; OH = fixed harness reset cost):
//   R2: OH + T_A         = 636.9 us   (A = int2, 2 samples/thread)
//   R3: OH + T_A + T_B   = 731.5 us   => T_B = 94.6 us EXACT
//       (B = int4, 4 samples/thread, 1954 blocks) = 512 MB/94.6us = 5.41 TB/s
//       vs 6.4-6.5 TB/s harness fills => ~85% of demonstrated ceiling.
//   R4: OH + T_C         = 639.1 us   (C = grid-stride int4, 1024 blocks)
//       => T_C = T_A + 2.2 us. Ambiguous: either OH~542 and ALL kernels are
//       ~95us (H1), or OH~479 and A,C are ~160us (H2).
// R5 = B alone: dur = OH + 94.6 exactly => measures OH, resolves H1/H2, and
// scores our fastest-known kernel. Predict dur ~637 (H1) or ~574 (H2).
//
// CORRECTNESS-CRITICAL (absmax 0.0 in R1-R4): replicate numpy's pairwise_sum
// for n=63 — 8 accumulators over rows 0..55 (r[k] sums rows k, k+8, ..,
// k+48), combine ((r0+r1)+(r2+r3))+((r4+r5)+(r6+r7)), then sequential tail
// rows 56..62 — so c1/c0 are BIT-EXACT vs the reference and the (c1 > c0)
// sign comparison cannot flip on near-ties. Do NOT reassociate / fast-math.

#define NM 63

__global__ __launch_bounds__(256, 4) void hbv_kernel_b(
    const int* __restrict__ votes, const float* __restrict__ wts,
    int* __restrict__ out, int n)
{
    __shared__ float ws[64];
    if (threadIdx.x < NM) ws[threadIdx.x] = wts[threadIdx.x];
    __syncthreads();

    const size_t t  = (size_t)blockIdx.x * blockDim.x + threadIdx.x;
    const size_t j0 = t * 4;
    if (j0 >= (size_t)n) return;

    const size_t row = (size_t)n;

    // numpy pairwise accumulators: r[k] sums rows k, k+8, ..., k+48
    float r1[8][4], r0[8][4];
#pragma unroll
    for (int k = 0; k < 8; ++k)
#pragma unroll
        for (int s = 0; s < 4; ++s) { r1[k][s] = 0.0f; r0[k][s] = 0.0f; }

    // Rows 0..55 in blocks of 8; unroll 1 keeps 8 int4 loads in flight.
#pragma unroll 1
    for (int b = 0; b < 7; ++b) {
        int4 v[8];
#pragma unroll
        for (int k = 0; k < 8; ++k)
            v[k] = *(const int4*)(votes + (size_t)(8 * b + k) * row + j0);
#pragma unroll
        for (int k = 0; k < 8; ++k) {
            const float wi = ws[8 * b + k];
            const int vv[4] = {v[k].x, v[k].y, v[k].z, v[k].w};
#pragma unroll
            for (int s = 0; s < 4; ++s) {
                r1[k][s] += (vv[s] != 0) ? wi : 0.0f;
                r0[k][s] += (vv[s] == 0) ? wi : 0.0f;
            }
        }
    }

    // numpy combine order
    float c1[4], c0[4];
#pragma unroll
    for (int s = 0; s < 4; ++s) {
        c1[s] = ((r1[0][s] + r1[1][s]) + (r1[2][s] + r1[3][s]))
              + ((r1[4][s] + r1[5][s]) + (r1[6][s] + r1[7][s]));
        c0[s] = ((r0[0][s] + r0[1][s]) + (r0[2][s] + r0[3][s]))
              + ((r0[4][s] + r0[5][s]) + (r0[6][s] + r0[7][s]));
    }

    // tail rows 56..62, sequential (numpy tail loop)
    {
        int4 v[7];
#pragma unroll
        for (int i = 0; i < 7; ++i)
            v[i] = *(const int4*)(votes + (size_t)(56 + i) * row + j0);
#pragma unroll
        for (int i = 0; i < 7; ++i) {
            const float wi = ws[56 + i];
            const int vv[4] = {v[i].x, v[i].y, v[i].z, v[i].w};
#pragma unroll
            for (int s = 0; s < 4; ++s) {
                c1[s] += (vv[s] != 0) ? wi : 0.0f;
                c0[s] += (vv[s] == 0) ? wi : 0.0f;
            }
        }
    }

    int4 res;
    res.x = (c1[0] > c0[0]) ? 1 : 0;
    res.y = (c1[1] > c0[1]) ? 1 : 0;
    res.z = (c1[2] > c0[2]) ? 1 : 0;
    res.w = (c1[3] > c0[3]) ? 1 : 0;
    *(int4*)(out + j0) = res;
}

extern "C" void kernel_launch(void* const* d_in, const int* in_sizes, int n_in,
                              void* d_out, int out_size, void* d_ws, size_t ws_size,
                              hipStream_t stream)
{
    const int*   votes = (const int*)d_in[0];
    const float* wts   = (const float*)d_in[1];
    int*         out   = (int*)d_out;
    const int n = out_size;                 // N_SAMPLES = 2,000,000

    const int threads  = 256;
    const int nthreads = (n + 3) / 4;       // one thread per 4 samples
    const int blocks   = (nthreads + threads - 1) / threads;   // 1954

    hipLaunchKernelGGL(hbv_kernel_b, dim3(blocks), dim3(threads), 0, stream,
                       votes, wts, out, n);
}

// Round 7
// 607.014 us; speedup vs baseline: 1.0576x; 1.0576x over previous
//
#include <hip/hip_runtime.h>

// HardBinaryVote: votes (63, N) int32 in {0,1}; weights (63,) fp32.
// out[j] = (sum_{v[i][j]==1} w[i]) > (sum_{v[i][j]==0} w[i]) ? 1 : 0  (int32)
//
// MEASUREMENT LEDGER (exact, differential rounds):
//   OH (harness reset: ws fill 310us + input restore + misc) = 547.4 us
//     [R5: 642.0 = OH + T_B with T_B = 94.6 exact from R3-R2]
//   T_A (int2, 256thr, 3907 blk)      = 89.5 us  (5.7 TB/s)
//   T_C (int4 grid-stride, 1024 blk)  = 91.7 us
//   T_B (int4, 256thr, 1954 blk)      = 94.6 us  (5.4 TB/s)
//   Harness's own 2GB fills run at 6.4-6.5 TB/s => kernel floor ~80 us,
//   scored floor ~627 us.
// R6 failed to COMPILE: __builtin_nontemporal_load rejects HIP_vector_type
// pointers -- needs a native clang ext_vector_type. R7 = same experiment,
// loads via `int __attribute__((ext_vector_type(4)))` (layout-identical to
// int4): (1) 64-thread blocks -> 7813 blocks (fine dispatch granularity;
// finest-grained A was fastest) and (2) nontemporal votes loads (zero-reuse
// stream, no L2 allocate). T_D = dur - 547.4 exactly.
//
// CORRECTNESS-CRITICAL (absmax 0.0 in R1-R5): replicate numpy's pairwise_sum
// for n=63 — 8 accumulators over rows 0..55 (r[k] sums rows k, k+8, ..,
// k+48), combine ((r0+r1)+(r2+r3))+((r4+r5)+(r6+r7)), then sequential tail
// rows 56..62 — so c1/c0 are BIT-EXACT vs the reference and the (c1 > c0)
// sign comparison cannot flip on near-ties. nt loads do not change values.
// Do NOT reassociate / fast-math.

#define NM 63

typedef int v4i __attribute__((ext_vector_type(4)));

__global__ __launch_bounds__(64, 4) void hbv_kernel_d(
    const int* __restrict__ votes, const float* __restrict__ wts,
    int* __restrict__ out, int n)
{
    __shared__ float ws[64];
    if (threadIdx.x < NM) ws[threadIdx.x] = wts[threadIdx.x];
    __syncthreads();

    const size_t t  = (size_t)blockIdx.x * blockDim.x + threadIdx.x;
    const size_t j0 = t * 4;
    if (j0 >= (size_t)n) return;

    const size_t row = (size_t)n;

    // numpy pairwise accumulators: r[k] sums rows k, k+8, ..., k+48
    float r1[8][4], r0[8][4];
#pragma unroll
    for (int k = 0; k < 8; ++k)
#pragma unroll
        for (int s = 0; s < 4; ++s) { r1[k][s] = 0.0f; r0[k][s] = 0.0f; }

    // Rows 0..55 in blocks of 8; unroll 1 keeps 8 int4 nt-loads in flight.
#pragma unroll 1
    for (int b = 0; b < 7; ++b) {
        v4i v[8];
#pragma unroll
        for (int k = 0; k < 8; ++k)
            v[k] = __builtin_nontemporal_load(
                (const v4i*)(votes + (size_t)(8 * b + k) * row + j0));
#pragma unroll
        for (int k = 0; k < 8; ++k) {
            const float wi = ws[8 * b + k];
#pragma unroll
            for (int s = 0; s < 4; ++s) {
                r1[k][s] += (v[k][s] != 0) ? wi : 0.0f;
                r0[k][s] += (v[k][s] == 0) ? wi : 0.0f;
            }
        }
    }

    // numpy combine order
    float c1[4], c0[4];
#pragma unroll
    for (int s = 0; s < 4; ++s) {
        c1[s] = ((r1[0][s] + r1[1][s]) + (r1[2][s] + r1[3][s]))
              + ((r1[4][s] + r1[5][s]) + (r1[6][s] + r1[7][s]));
        c0[s] = ((r0[0][s] + r0[1][s]) + (r0[2][s] + r0[3][s]))
              + ((r0[4][s] + r0[5][s]) + (r0[6][s] + r0[7][s]));
    }

    // tail rows 56..62, sequential (numpy tail loop)
    {
        v4i v[7];
#pragma unroll
        for (int i = 0; i < 7; ++i)
            v[i] = __builtin_nontemporal_load(
                (const v4i*)(votes + (size_t)(56 + i) * row + j0));
#pragma unroll
        for (int i = 0; i < 7; ++i) {
            const float wi = ws[56 + i];
#pragma unroll
            for (int s = 0; s < 4; ++s) {
                c1[s] += (v[i][s] != 0) ? wi : 0.0f;
                c0[s] += (v[i][s] == 0) ? wi : 0.0f;
            }
        }
    }

    v4i res;
    res[0] = (c1[0] > c0[0]) ? 1 : 0;
    res[1] = (c1[1] > c0[1]) ? 1 : 0;
    res[2] = (c1[2] > c0[2]) ? 1 : 0;
    res[3] = (c1[3] > c0[3]) ? 1 : 0;
    *(v4i*)(out + j0) = res;
}

extern "C" void kernel_launch(void* const* d_in, const int* in_sizes, int n_in,
                              void* d_out, int out_size, void* d_ws, size_t ws_size,
                              hipStream_t stream)
{
    const int*   votes = (const int*)d_in[0];
    const float* wts   = (const float*)d_in[1];
    int*         out   = (int*)d_out;
    const int n = out_size;                 // N_SAMPLES = 2,000,000

    const int threads  = 64;                // 1 wave/block, fine granularity
    const int nthreads = (n + 3) / 4;       // one thread per 4 samples
    const int blocks   = (nthreads + threads - 1) / threads;   // 7813

    hipLaunchKernelGGL(hbv_kernel_d, dim3(blocks), dim3(threads), 0, stream,
                       votes, wts, out, n);
}

// Round 8
// 603.566 us; speedup vs baseline: 1.0636x; 1.0057x over previous
//
#include <hip/hip_runtime.h>

// HardBinaryVote: votes (63, N) int32 in {0,1}; weights (63,) fp32.
// out[j] = (sum_{v[i][j]==1} w[i]) > (sum_{v[i][j]==0} w[i]) ? 1 : 0  (int32)
//
// MEASUREMENT LEDGER (exact, differential rounds):
//   OH (harness reset: ~2GB ws fill 310us + 504MB input restore + misc)
//      = 547.4 us   [R5: 642.0 = OH + T_B, T_B = 94.6 exact from R3-R2]
//   T_A (int2, 256thr)                 = 89.5 us
//   T_C (int4 grid-stride, 1024 blk)   = 91.7 us
//   T_B (int4, 256thr, 1954 blk)       = 94.6 us   (5.4 TB/s)
//   T_D (int4, 64thr, 7813 blk, nt ld) = 59.6 us   (R7: 607.0)
//       => effective 8.6 TB/s > 8.0 TB/s HBM peak: ~half of votes is served
//       from L3 (restore writes 504 MB right before us; 256 MiB Infinity
//       Cache retains rows ~32..62). nt loads probe-but-don't-allocate,
//       so no pollution and no next-iteration invalidation cost.
// R8 = D + nontemporal STORE on out (same argument, 8 MB write stream).
// Kernel-side floor from the L3-split model ~40-45 us; VALU ~10% busy.
// If R8 lands within noise of 607, we're at the mixed L3+HBM ceiling.
//
// CORRECTNESS-CRITICAL (absmax 0.0 in R1-R5, R7): replicate numpy's
// pairwise_sum for n=63 — 8 accumulators over rows 0..55 (r[k] sums rows
// k, k+8, .., k+48), combine ((r0+r1)+(r2+r3))+((r4+r5)+(r6+r7)), then
// sequential tail rows 56..62 — so c1/c0 are BIT-EXACT vs the reference and
// the (c1 > c0) sign comparison cannot flip on near-ties. nt load/store do
// not change values. Do NOT reassociate / fast-math.

#define NM 63

typedef int v4i __attribute__((ext_vector_type(4)));

__global__ __launch_bounds__(64, 4) void hbv_kernel_e(
    const int* __restrict__ votes, const float* __restrict__ wts,
    int* __restrict__ out, int n)
{
    __shared__ float ws[64];
    if (threadIdx.x < NM) ws[threadIdx.x] = wts[threadIdx.x];
    __syncthreads();

    const size_t t  = (size_t)blockIdx.x * blockDim.x + threadIdx.x;
    const size_t j0 = t * 4;
    if (j0 >= (size_t)n) return;

    const size_t row = (size_t)n;

    // numpy pairwise accumulators: r[k] sums rows k, k+8, ..., k+48
    float r1[8][4], r0[8][4];
#pragma unroll
    for (int k = 0; k < 8; ++k)
#pragma unroll
        for (int s = 0; s < 4; ++s) { r1[k][s] = 0.0f; r0[k][s] = 0.0f; }

    // Rows 0..55 in blocks of 8; unroll 1 keeps 8 int4 nt-loads in flight.
#pragma unroll 1
    for (int b = 0; b < 7; ++b) {
        v4i v[8];
#pragma unroll
        for (int k = 0; k < 8; ++k)
            v[k] = __builtin_nontemporal_load(
                (const v4i*)(votes + (size_t)(8 * b + k) * row + j0));
#pragma unroll
        for (int k = 0; k < 8; ++k) {
            const float wi = ws[8 * b + k];
#pragma unroll
            for (int s = 0; s < 4; ++s) {
                r1[k][s] += (v[k][s] != 0) ? wi : 0.0f;
                r0[k][s] += (v[k][s] == 0) ? wi : 0.0f;
            }
        }
    }

    // numpy combine order
    float c1[4], c0[4];
#pragma unroll
    for (int s = 0; s < 4; ++s) {
        c1[s] = ((r1[0][s] + r1[1][s]) + (r1[2][s] + r1[3][s]))
              + ((r1[4][s] + r1[5][s]) + (r1[6][s] + r1[7][s]));
        c0[s] = ((r0[0][s] + r0[1][s]) + (r0[2][s] + r0[3][s]))
              + ((r0[4][s] + r0[5][s]) + (r0[6][s] + r0[7][s]));
    }

    // tail rows 56..62, sequential (numpy tail loop)
    {
        v4i v[7];
#pragma unroll
        for (int i = 0; i < 7; ++i)
            v[i] = __builtin_nontemporal_load(
                (const v4i*)(votes + (size_t)(56 + i) * row + j0));
#pragma unroll
        for (int i = 0; i < 7; ++i) {
            const float wi = ws[56 + i];
#pragma unroll
            for (int s = 0; s < 4; ++s) {
                c1[s] += (v[i][s] != 0) ? wi : 0.0f;
                c0[s] += (v[i][s] == 0) ? wi : 0.0f;
            }
        }
    }

    v4i res;
    res[0] = (c1[0] > c0[0]) ? 1 : 0;
    res[1] = (c1[1] > c0[1]) ? 1 : 0;
    res[2] = (c1[2] > c0[2]) ? 1 : 0;
    res[3] = (c1[3] > c0[3]) ? 1 : 0;
    __builtin_nontemporal_store(res, (v4i*)(out + j0));
}

extern "C" void kernel_launch(void* const* d_in, const int* in_sizes, int n_in,
                              void* d_out, int out_size, void* d_ws, size_t ws_size,
                              hipStream_t stream)
{
    const int*   votes = (const int*)d_in[0];
    const float* wts   = (const float*)d_in[1];
    int*         out   = (int*)d_out;
    const int n = out_size;                 // N_SAMPLES = 2,000,000

    const int threads  = 64;                // 1 wave/block, fine granularity
    const int nthreads = (n + 3) / 4;       // one thread per 4 samples
    const int blocks   = (nthreads + threads - 1) / threads;   // 7813

    hipLaunchKernelGGL(hbv_kernel_e, dim3(blocks), dim3(threads), 0, stream,
                       votes, wts, out, n);
}